// Round 2
// baseline (1734.653 us; speedup 1.0000x reference)
//
#include <hip/hip_runtime.h>

#define HID 128
#define NNODE 50000
#define NEDGE 640000

// ---------------------------------------------------------------- embed: x = emb[z]
static __global__ void embed_kernel(const int* __restrict__ z,
                                    const float* __restrict__ emb,
                                    float* __restrict__ x) {
  int i = blockIdx.x * 256 + threadIdx.x;          // over NNODE*32 float4 groups
  const int total = NNODE * (HID / 4);
  if (i >= total) return;
  int node = i >> 5;
  int c = i & 31;
  ((float4*)x)[i] = ((const float4*)emb)[(size_t)z[node] * 32 + c];
}

// ---------------------------------------------------------------- CSR build
static __global__ void hist_kernel(const int* __restrict__ dst, int* __restrict__ deg) {
  int i = blockIdx.x * 256 + threadIdx.x;
  if (i < NEDGE) atomicAdd(&deg[dst[i]], 1);
}

static __global__ void scan_kernel(const int* __restrict__ deg,
                                   int* __restrict__ row_ptr,
                                   int* __restrict__ cursor) {
  __shared__ int sums[1024];
  int t = threadIdx.x;
  const int per = (NNODE + 1023) / 1024;           // 49
  int base = t * per;
  int s = 0;
  for (int i = 0; i < per; ++i) {
    int idx = base + i;
    if (idx < NNODE) s += deg[idx];
  }
  sums[t] = s;
  __syncthreads();
  for (int off = 1; off < 1024; off <<= 1) {
    int v = (t >= off) ? sums[t - off] : 0;
    __syncthreads();
    if (t >= off) sums[t] += v;
    __syncthreads();
  }
  int run = (t == 0) ? 0 : sums[t - 1];            // exclusive prefix
  for (int i = 0; i < per; ++i) {
    int idx = base + i;
    if (idx < NNODE) {
      row_ptr[idx] = run;
      cursor[idx] = run;
      run += deg[idx];
    }
  }
  if (t == 1023) row_ptr[NNODE] = run;             // == NEDGE
}

static __global__ void fill_kernel(const int* __restrict__ src, const int* __restrict__ dst,
                                   int* __restrict__ cursor, int2* __restrict__ elist) {
  int i = blockIdx.x * 256 + threadIdx.x;
  if (i < NEDGE) {
    int d = dst[i];
    int p = atomicAdd(&cursor[d], 1);
    elist[p] = make_int2(i, src[i]);               // (edge id, src node)
  }
}

// ---------------------------------------------------------------- fused conv:
// gather (agg+x into LDS) -> t=relu(A@W1+b1) -> h=t@W2+b2 (+relu) -> +x residual
// LDS = As 33.8K + Wb 16.4K = 50.2 KB -> 3 blocks/CU = 3 waves/SIMD.
static __global__ __launch_bounds__(256) void conv_fused(
    const float* __restrict__ x, const float* __restrict__ ea,
    const int* __restrict__ rowptr, const int2* __restrict__ elist,
    const float* __restrict__ W1, const float* __restrict__ b1,
    const float* __restrict__ W2, const float* __restrict__ b2,
    float* __restrict__ xout, int relu_out) {
  __shared__ float As[64 * 132];                   // ld=132 (528B = 33*16B, float4-aligned rows)
  __shared__ float Wb[32 * 128];                   // one 32-k-row chunk of W
  const int tid = threadIdx.x;
  const int row0 = blockIdx.x * 64;
  const int wv = tid >> 6, ln = tid & 63;

  // ---- gather phase: As[n][:] = x[node] + sum_{e->node} relu(x[src]+ea[e])
  const float2* x2 = (const float2*)x;
  const float2* e2 = (const float2*)ea;
  for (int n = wv; n < 64; n += 4) {               // 16 nodes per wave
    int node = row0 + n;
    float2 acc = make_float2(0.f, 0.f);
    if (node < NNODE) {
      acc = x2[(size_t)node * 64 + ln];
      int j  = rowptr[node];
      int je = rowptr[node + 1];
      for (; j < je; ++j) {
        int2 es = elist[j];                        // wave-uniform
        float2 xv = x2[(size_t)es.y * 64 + ln];
        float2 ev = e2[(size_t)es.x * 64 + ln];
        acc.x += fmaxf(xv.x + ev.x, 0.f);
        acc.y += fmaxf(xv.y + ev.y, 0.f);
      }
    }
    *(float2*)&As[n * 132 + ln * 2] = acc;
  }

  const int rg = tid >> 4, cg = tid & 15;
  const int rb = rg * 4, cb = cg * 8;

  float acc[4][8];
#pragma unroll
  for (int r = 0; r < 4; ++r)
#pragma unroll
    for (int c = 0; c < 8; ++c) acc[r][c] = 0.f;

  // ---- GEMM 1: acc = A @ W1, chunked over k (4 chunks x 32 rows)
  for (int ch = 0; ch < 4; ++ch) {
    __syncthreads();                               // As writes (ch=0) / prior Wb reads done
    for (int i = tid; i < 32 * 32; i += 256)
      ((float4*)Wb)[i] = ((const float4*)(W1 + ch * 32 * 128))[i];
    __syncthreads();
    const int k0 = ch * 32;
    for (int k = 0; k < 32; k += 4) {
      float4 a0 = *(const float4*)&As[(rb + 0) * 132 + k0 + k];
      float4 a1 = *(const float4*)&As[(rb + 1) * 132 + k0 + k];
      float4 a2 = *(const float4*)&As[(rb + 2) * 132 + k0 + k];
      float4 a3 = *(const float4*)&As[(rb + 3) * 132 + k0 + k];
#pragma unroll
      for (int kk = 0; kk < 4; ++kk) {
        float4 w0 = *(const float4*)&Wb[(k + kk) * 128 + cb];
        float4 w1 = *(const float4*)&Wb[(k + kk) * 128 + cb + 4];
        float av[4] = {((const float*)&a0)[kk], ((const float*)&a1)[kk],
                       ((const float*)&a2)[kk], ((const float*)&a3)[kk]};
#pragma unroll
        for (int r = 0; r < 4; ++r) {
          acc[r][0] += av[r] * w0.x; acc[r][1] += av[r] * w0.y;
          acc[r][2] += av[r] * w0.z; acc[r][3] += av[r] * w0.w;
          acc[r][4] += av[r] * w1.x; acc[r][5] += av[r] * w1.y;
          acc[r][6] += av[r] * w1.z; acc[r][7] += av[r] * w1.w;
        }
      }
    }
  }
  __syncthreads();                                 // all GEMM1 As reads done

  // t = relu(acc + b1) -> back into As
  {
    float4 bb0 = ((const float4*)b1)[cb >> 2];
    float4 bb1 = ((const float4*)b1)[(cb >> 2) + 1];
    float bv[8] = {bb0.x, bb0.y, bb0.z, bb0.w, bb1.x, bb1.y, bb1.z, bb1.w};
#pragma unroll
    for (int r = 0; r < 4; ++r) {
      float t0[8];
#pragma unroll
      for (int c = 0; c < 8; ++c) t0[c] = fmaxf(acc[r][c] + bv[c], 0.f);
      *(float4*)&As[(rb + r) * 132 + cb]     = make_float4(t0[0], t0[1], t0[2], t0[3]);
      *(float4*)&As[(rb + r) * 132 + cb + 4] = make_float4(t0[4], t0[5], t0[6], t0[7]);
    }
  }

#pragma unroll
  for (int r = 0; r < 4; ++r)
#pragma unroll
    for (int c = 0; c < 8; ++c) acc[r][c] = 0.f;

  // ---- GEMM 2: acc = t @ W2, chunked
  for (int ch = 0; ch < 4; ++ch) {
    __syncthreads();                               // t writes (ch=0) / prior Wb reads done
    for (int i = tid; i < 32 * 32; i += 256)
      ((float4*)Wb)[i] = ((const float4*)(W2 + ch * 32 * 128))[i];
    __syncthreads();
    const int k0 = ch * 32;
    for (int k = 0; k < 32; k += 4) {
      float4 a0 = *(const float4*)&As[(rb + 0) * 132 + k0 + k];
      float4 a1 = *(const float4*)&As[(rb + 1) * 132 + k0 + k];
      float4 a2 = *(const float4*)&As[(rb + 2) * 132 + k0 + k];
      float4 a3 = *(const float4*)&As[(rb + 3) * 132 + k0 + k];
#pragma unroll
      for (int kk = 0; kk < 4; ++kk) {
        float4 w0 = *(const float4*)&Wb[(k + kk) * 128 + cb];
        float4 w1 = *(const float4*)&Wb[(k + kk) * 128 + cb + 4];
        float av[4] = {((const float*)&a0)[kk], ((const float*)&a1)[kk],
                       ((const float*)&a2)[kk], ((const float*)&a3)[kk]};
#pragma unroll
        for (int r = 0; r < 4; ++r) {
          acc[r][0] += av[r] * w0.x; acc[r][1] += av[r] * w0.y;
          acc[r][2] += av[r] * w0.z; acc[r][3] += av[r] * w0.w;
          acc[r][4] += av[r] * w1.x; acc[r][5] += av[r] * w1.y;
          acc[r][6] += av[r] * w1.z; acc[r][7] += av[r] * w1.w;
        }
      }
    }
  }

  // epilogue: bias, optional relu, residual, store
  {
    float4 bb0 = ((const float4*)b2)[cb >> 2];
    float4 bb1 = ((const float4*)b2)[(cb >> 2) + 1];
    float bv[8] = {bb0.x, bb0.y, bb0.z, bb0.w, bb1.x, bb1.y, bb1.z, bb1.w};
#pragma unroll
    for (int r = 0; r < 4; ++r) {
      int row = row0 + rb + r;
      if (row < NNODE) {
        float4 xv0 = ((const float4*)x)[(size_t)row * 32 + (cb >> 2)];
        float4 xv1 = ((const float4*)x)[(size_t)row * 32 + (cb >> 2) + 1];
        float o[8];
#pragma unroll
        for (int c = 0; c < 8; ++c) {
          float v = acc[r][c] + bv[c];
          if (relu_out) v = fmaxf(v, 0.f);
          o[c] = v;
        }
        o[0] += xv0.x; o[1] += xv0.y; o[2] += xv0.z; o[3] += xv0.w;
        o[4] += xv1.x; o[5] += xv1.y; o[6] += xv1.z; o[7] += xv1.w;
        ((float4*)xout)[(size_t)row * 32 + (cb >> 2)]     = make_float4(o[0], o[1], o[2], o[3]);
        ((float4*)xout)[(size_t)row * 32 + (cb >> 2) + 1] = make_float4(o[4], o[5], o[6], o[7]);
      }
    }
  }
}

extern "C" void kernel_launch(void* const* d_in, const int* in_sizes, int n_in,
                              void* d_out, int out_size, void* d_ws, size_t ws_size,
                              hipStream_t stream) {
  const int*   z   = (const int*)d_in[0];
  const int*   ei  = (const int*)d_in[1];     // [2, E] row-major
  const float* ea  = (const float*)d_in[2];
  const float* emb = (const float*)d_in[3];
  const float* W1  = (const float*)d_in[4];
  const float* b1  = (const float*)d_in[5];
  const float* W2  = (const float*)d_in[6];
  const float* b2  = (const float*)d_in[7];
  float* outp = (float*)d_out;

  char* ws = (char*)d_ws;
  float* xbuf   = (float*)(ws + 0);            // 25,600,000 B
  float* obuf   = (float*)(ws + 25600000);     // 25,600,000 B
  int*   deg    = (int*)  (ws + 51200000);     //    200,000 B
  int*   cursor = (int*)  (ws + 51400000);     //    200,000 B
  int*   rowptr = (int*)  (ws + 51600000);     //    200,004 B
  int2*  elist  = (int2*) (ws + 51800016);     //  5,120,000 B  (end ~56.9 MB)

  const int* srcv = ei;
  const int* dstv = ei + NEDGE;

  hipMemsetAsync(deg, 0, NNODE * sizeof(int), stream);
  embed_kernel<<<(NNODE * 32 + 255) / 256, 256, 0, stream>>>(z, emb, xbuf);
  hist_kernel<<<(NEDGE + 255) / 256, 256, 0, stream>>>(dstv, deg);
  scan_kernel<<<1, 1024, 0, stream>>>(deg, rowptr, cursor);
  fill_kernel<<<(NEDGE + 255) / 256, 256, 0, stream>>>(srcv, dstv, cursor, elist);

  const int nblk = (NNODE + 63) / 64;          // 782
  // conv0: xbuf -> obuf ; conv1: obuf -> xbuf ; conv2: xbuf -> d_out
  const float* xin[3]  = {xbuf, obuf, xbuf};
  float*       xout[3] = {obuf, xbuf, outp};
  for (int i = 0; i < 3; ++i) {
    conv_fused<<<nblk, 256, 0, stream>>>(
        xin[i], ea, rowptr, elist,
        W1 + (size_t)i * HID * HID, b1 + (size_t)i * HID,
        W2 + (size_t)i * HID * HID, b2 + (size_t)i * HID,
        xout[i], (i < 2) ? 1 : 0);
  }
}

// Round 3
// 1076.220 us; speedup vs baseline: 1.6118x; 1.6118x over previous
//
#include <hip/hip_runtime.h>

#define HID 128
#define NNODE 50000
#define NEDGE 640000

// ---------------------------------------------------------------- embed: x = emb[z]
static __global__ void embed_kernel(const int* __restrict__ z,
                                    const float* __restrict__ emb,
                                    float* __restrict__ x) {
  int i = blockIdx.x * 256 + threadIdx.x;          // over NNODE*32 float4 groups
  const int total = NNODE * (HID / 4);
  if (i >= total) return;
  int node = i >> 5;
  int c = i & 31;
  ((float4*)x)[i] = ((const float4*)emb)[(size_t)z[node] * 32 + c];
}

// ---------------------------------------------------------------- CSR build
static __global__ void hist_kernel(const int* __restrict__ dst, int* __restrict__ deg) {
  int i = blockIdx.x * 256 + threadIdx.x;
  if (i < NEDGE) atomicAdd(&deg[dst[i]], 1);
}

static __global__ void scan_kernel(const int* __restrict__ deg,
                                   int* __restrict__ row_ptr,
                                   int* __restrict__ cursor) {
  __shared__ int sums[1024];
  int t = threadIdx.x;
  const int per = (NNODE + 1023) / 1024;           // 49
  int base = t * per;
  int s = 0;
  for (int i = 0; i < per; ++i) {
    int idx = base + i;
    if (idx < NNODE) s += deg[idx];
  }
  sums[t] = s;
  __syncthreads();
  for (int off = 1; off < 1024; off <<= 1) {
    int v = (t >= off) ? sums[t - off] : 0;
    __syncthreads();
    if (t >= off) sums[t] += v;
    __syncthreads();
  }
  int run = (t == 0) ? 0 : sums[t - 1];            // exclusive prefix
  for (int i = 0; i < per; ++i) {
    int idx = base + i;
    if (idx < NNODE) {
      row_ptr[idx] = run;
      cursor[idx] = run;
      run += deg[idx];
    }
  }
  if (t == 1023) row_ptr[NNODE] = run;             // == NEDGE
}

static __global__ void fill_kernel(const int* __restrict__ src, const int* __restrict__ dst,
                                   int* __restrict__ cursor, int2* __restrict__ elist) {
  int i = blockIdx.x * 256 + threadIdx.x;
  if (i < NEDGE) {
    int d = dst[i];
    int p = atomicAdd(&cursor[d], 1);
    elist[p] = make_int2(i, src[i]);               // (edge id, src node)
  }
}

// ---------------------------------------------------------------- gather:
// out[n] = x[n] + sum_{e->n} relu(x[src]+ea[e]);  1 node/wave, edge unroll x4
// with 4 independent accumulators -> 8 outstanding loads per wave.
static __global__ __launch_bounds__(256) void gather_kernel(
    const float* __restrict__ x, const float* __restrict__ ea,
    const int* __restrict__ row_ptr, const int2* __restrict__ elist,
    float* __restrict__ out) {
  int wave = threadIdx.x >> 6;                     // 4 waves/block, 1 node/wave
  int lane = threadIdx.x & 63;
  int node = blockIdx.x * 4 + wave;
  if (node >= NNODE) return;
  const float2* x2 = (const float2*)x;
  const float2* e2 = (const float2*)ea;
  float2 a0 = x2[(size_t)node * 64 + lane];        // out = agg + x : init with x
  float2 a1 = make_float2(0.f, 0.f);
  float2 a2 = make_float2(0.f, 0.f);
  float2 a3 = make_float2(0.f, 0.f);
  int j  = row_ptr[node];
  int je = row_ptr[node + 1];
  for (; j + 4 <= je; j += 4) {
    int2 e0 = elist[j], e1 = elist[j + 1], e2i = elist[j + 2], e3 = elist[j + 3];
    float2 xv0 = x2[(size_t)e0.y * 64 + lane];
    float2 ev0 = e2[(size_t)e0.x * 64 + lane];
    float2 xv1 = x2[(size_t)e1.y * 64 + lane];
    float2 ev1 = e2[(size_t)e1.x * 64 + lane];
    float2 xv2 = x2[(size_t)e2i.y * 64 + lane];
    float2 ev2 = e2[(size_t)e2i.x * 64 + lane];
    float2 xv3 = x2[(size_t)e3.y * 64 + lane];
    float2 ev3 = e2[(size_t)e3.x * 64 + lane];
    a0.x += fmaxf(xv0.x + ev0.x, 0.f); a0.y += fmaxf(xv0.y + ev0.y, 0.f);
    a1.x += fmaxf(xv1.x + ev1.x, 0.f); a1.y += fmaxf(xv1.y + ev1.y, 0.f);
    a2.x += fmaxf(xv2.x + ev2.x, 0.f); a2.y += fmaxf(xv2.y + ev2.y, 0.f);
    a3.x += fmaxf(xv3.x + ev3.x, 0.f); a3.y += fmaxf(xv3.y + ev3.y, 0.f);
  }
  for (; j < je; ++j) {
    int2 es = elist[j];
    float2 xv = x2[(size_t)es.y * 64 + lane];
    float2 ev = e2[(size_t)es.x * 64 + lane];
    a0.x += fmaxf(xv.x + ev.x, 0.f);
    a0.y += fmaxf(xv.y + ev.y, 0.f);
  }
  a0.x += a1.x + a2.x + a3.x;
  a0.y += a1.y + a2.y + a3.y;
  ((float2*)out)[(size_t)node * 64 + lane] = a0;
}

// ---------------------------------------------------------------- MLP: xout = x + [relu?](relu(in@W1+b1)@W2+b2)
// 64-row tile/block; W staged in 32-row chunks (LDS 50.2 KB -> 3 blocks/CU).
static __global__ __launch_bounds__(256) void mlp_kernel(
    const float* __restrict__ in, const float* __restrict__ xres,
    const float* __restrict__ W1, const float* __restrict__ b1,
    const float* __restrict__ W2, const float* __restrict__ b2,
    float* __restrict__ xout, int relu_out) {
  __shared__ float As[64 * 132];                   // ld=132: float4-aligned rows, no bank conflicts
  __shared__ float Wb[32 * 128];                   // one 32-k-row chunk of W
  const int tid = threadIdx.x;
  const int row0 = blockIdx.x * 64;

  // stage A tile (zeros for tail rows)
  for (int i = tid; i < 64 * 32; i += 256) {
    int r = i >> 5, c = i & 31;
    float4 v = make_float4(0.f, 0.f, 0.f, 0.f);
    int row = row0 + r;
    if (row < NNODE) v = ((const float4*)in)[(size_t)row * 32 + c];
    *(float4*)&As[r * 132 + c * 4] = v;
  }

  const int rg = tid >> 4, cg = tid & 15;
  const int rb = rg * 4, cb = cg * 8;

  float acc[4][8];
#pragma unroll
  for (int r = 0; r < 4; ++r)
#pragma unroll
    for (int c = 0; c < 8; ++c) acc[r][c] = 0.f;

  // ---- GEMM 1: acc = A @ W1, chunked over k
  for (int ch = 0; ch < 4; ++ch) {
    __syncthreads();
    for (int i = tid; i < 32 * 32; i += 256)
      ((float4*)Wb)[i] = ((const float4*)(W1 + ch * 32 * 128))[i];
    __syncthreads();
    const int k0 = ch * 32;
    for (int k = 0; k < 32; k += 4) {
      float4 a0 = *(const float4*)&As[(rb + 0) * 132 + k0 + k];
      float4 a1 = *(const float4*)&As[(rb + 1) * 132 + k0 + k];
      float4 a2 = *(const float4*)&As[(rb + 2) * 132 + k0 + k];
      float4 a3 = *(const float4*)&As[(rb + 3) * 132 + k0 + k];
#pragma unroll
      for (int kk = 0; kk < 4; ++kk) {
        float4 w0 = *(const float4*)&Wb[(k + kk) * 128 + cb];
        float4 w1 = *(const float4*)&Wb[(k + kk) * 128 + cb + 4];
        float av[4] = {((const float*)&a0)[kk], ((const float*)&a1)[kk],
                       ((const float*)&a2)[kk], ((const float*)&a3)[kk]};
#pragma unroll
        for (int r = 0; r < 4; ++r) {
          acc[r][0] += av[r] * w0.x; acc[r][1] += av[r] * w0.y;
          acc[r][2] += av[r] * w0.z; acc[r][3] += av[r] * w0.w;
          acc[r][4] += av[r] * w1.x; acc[r][5] += av[r] * w1.y;
          acc[r][6] += av[r] * w1.z; acc[r][7] += av[r] * w1.w;
        }
      }
    }
  }
  __syncthreads();                                 // all GEMM1 As reads done

  // t = relu(acc + b1) -> back into As
  {
    float4 bb0 = ((const float4*)b1)[cb >> 2];
    float4 bb1 = ((const float4*)b1)[(cb >> 2) + 1];
    float bv[8] = {bb0.x, bb0.y, bb0.z, bb0.w, bb1.x, bb1.y, bb1.z, bb1.w};
#pragma unroll
    for (int r = 0; r < 4; ++r) {
      float t0[8];
#pragma unroll
      for (int c = 0; c < 8; ++c) t0[c] = fmaxf(acc[r][c] + bv[c], 0.f);
      *(float4*)&As[(rb + r) * 132 + cb]     = make_float4(t0[0], t0[1], t0[2], t0[3]);
      *(float4*)&As[(rb + r) * 132 + cb + 4] = make_float4(t0[4], t0[5], t0[6], t0[7]);
    }
  }

#pragma unroll
  for (int r = 0; r < 4; ++r)
#pragma unroll
    for (int c = 0; c < 8; ++c) acc[r][c] = 0.f;

  // ---- GEMM 2: acc = t @ W2, chunked
  for (int ch = 0; ch < 4; ++ch) {
    __syncthreads();
    for (int i = tid; i < 32 * 32; i += 256)
      ((float4*)Wb)[i] = ((const float4*)(W2 + ch * 32 * 128))[i];
    __syncthreads();
    const int k0 = ch * 32;
    for (int k = 0; k < 32; k += 4) {
      float4 a0 = *(const float4*)&As[(rb + 0) * 132 + k0 + k];
      float4 a1 = *(const float4*)&As[(rb + 1) * 132 + k0 + k];
      float4 a2 = *(const float4*)&As[(rb + 2) * 132 + k0 + k];
      float4 a3 = *(const float4*)&As[(rb + 3) * 132 + k0 + k];
#pragma unroll
      for (int kk = 0; kk < 4; ++kk) {
        float4 w0 = *(const float4*)&Wb[(k + kk) * 128 + cb];
        float4 w1 = *(const float4*)&Wb[(k + kk) * 128 + cb + 4];
        float av[4] = {((const float*)&a0)[kk], ((const float*)&a1)[kk],
                       ((const float*)&a2)[kk], ((const float*)&a3)[kk]};
#pragma unroll
        for (int r = 0; r < 4; ++r) {
          acc[r][0] += av[r] * w0.x; acc[r][1] += av[r] * w0.y;
          acc[r][2] += av[r] * w0.z; acc[r][3] += av[r] * w0.w;
          acc[r][4] += av[r] * w1.x; acc[r][5] += av[r] * w1.y;
          acc[r][6] += av[r] * w1.z; acc[r][7] += av[r] * w1.w;
        }
      }
    }
  }

  // epilogue: bias, optional relu, residual, store
  {
    float4 bb0 = ((const float4*)b2)[cb >> 2];
    float4 bb1 = ((const float4*)b2)[(cb >> 2) + 1];
    float bv[8] = {bb0.x, bb0.y, bb0.z, bb0.w, bb1.x, bb1.y, bb1.z, bb1.w};
#pragma unroll
    for (int r = 0; r < 4; ++r) {
      int row = row0 + rb + r;
      if (row < NNODE) {
        float4 xv0 = ((const float4*)xres)[(size_t)row * 32 + (cb >> 2)];
        float4 xv1 = ((const float4*)xres)[(size_t)row * 32 + (cb >> 2) + 1];
        float o[8];
#pragma unroll
        for (int c = 0; c < 8; ++c) {
          float v = acc[r][c] + bv[c];
          if (relu_out) v = fmaxf(v, 0.f);
          o[c] = v;
        }
        o[0] += xv0.x; o[1] += xv0.y; o[2] += xv0.z; o[3] += xv0.w;
        o[4] += xv1.x; o[5] += xv1.y; o[6] += xv1.z; o[7] += xv1.w;
        ((float4*)xout)[(size_t)row * 32 + (cb >> 2)]     = make_float4(o[0], o[1], o[2], o[3]);
        ((float4*)xout)[(size_t)row * 32 + (cb >> 2) + 1] = make_float4(o[4], o[5], o[6], o[7]);
      }
    }
  }
}

extern "C" void kernel_launch(void* const* d_in, const int* in_sizes, int n_in,
                              void* d_out, int out_size, void* d_ws, size_t ws_size,
                              hipStream_t stream) {
  const int*   z   = (const int*)d_in[0];
  const int*   ei  = (const int*)d_in[1];     // [2, E] row-major
  const float* ea  = (const float*)d_in[2];
  const float* emb = (const float*)d_in[3];
  const float* W1  = (const float*)d_in[4];
  const float* b1  = (const float*)d_in[5];
  const float* W2  = (const float*)d_in[6];
  const float* b2  = (const float*)d_in[7];
  float* outp = (float*)d_out;

  char* ws = (char*)d_ws;
  float* xbuf   = (float*)(ws + 0);            // 25,600,000 B
  float* obuf   = (float*)(ws + 25600000);     // 25,600,000 B
  int*   deg    = (int*)  (ws + 51200000);     //    200,000 B
  int*   cursor = (int*)  (ws + 51400000);     //    200,000 B
  int*   rowptr = (int*)  (ws + 51600000);     //    200,004 B
  int2*  elist  = (int2*) (ws + 51800016);     //  5,120,000 B  (end ~56.9 MB)

  const int* srcv = ei;
  const int* dstv = ei + NEDGE;

  hipMemsetAsync(deg, 0, NNODE * sizeof(int), stream);
  embed_kernel<<<(NNODE * 32 + 255) / 256, 256, 0, stream>>>(z, emb, xbuf);
  hist_kernel<<<(NEDGE + 255) / 256, 256, 0, stream>>>(dstv, deg);
  scan_kernel<<<1, 1024, 0, stream>>>(deg, rowptr, cursor);
  fill_kernel<<<(NEDGE + 255) / 256, 256, 0, stream>>>(srcv, dstv, cursor, elist);

  for (int i = 0; i < 3; ++i) {
    gather_kernel<<<(NNODE + 3) / 4, 256, 0, stream>>>(xbuf, ea, rowptr, elist, obuf);
    float* xo = (i == 2) ? outp : xbuf;          // in-place residual write is
    mlp_kernel<<<(NNODE + 63) / 64, 256, 0, stream>>>(   // thread-private per row
        obuf, xbuf,
        W1 + (size_t)i * HID * HID, b1 + (size_t)i * HID,
        W2 + (size_t)i * HID * HID, b2 + (size_t)i * HID,
        xo, (i < 2) ? 1 : 0);
  }
}

// Round 4
// 967.507 us; speedup vs baseline: 1.7929x; 1.1124x over previous
//
#include <hip/hip_runtime.h>

#define HID 128
#define NNODE 50000
#define NEDGE 640000

typedef __attribute__((ext_vector_type(8))) short bf16x8;
typedef __attribute__((ext_vector_type(4))) float f32x4;

// ---------------------------------------------------------------- embed: x = emb[z]
static __global__ void embed_kernel(const int* __restrict__ z,
                                    const float* __restrict__ emb,
                                    float* __restrict__ x) {
  int i = blockIdx.x * 256 + threadIdx.x;
  const int total = NNODE * (HID / 4);
  if (i >= total) return;
  int node = i >> 5;
  int c = i & 31;
  ((float4*)x)[i] = ((const float4*)emb)[(size_t)z[node] * 32 + c];
}

// ---------------------------------------------------------------- CSR build
static __global__ void hist_kernel(const int* __restrict__ dst, int* __restrict__ deg) {
  int i = blockIdx.x * 256 + threadIdx.x;
  if (i < NEDGE) atomicAdd(&deg[dst[i]], 1);
}

static __global__ void scan_kernel(const int* __restrict__ deg,
                                   int* __restrict__ row_ptr,
                                   int* __restrict__ cursor) {
  __shared__ int sums[1024];
  int t = threadIdx.x;
  const int per = (NNODE + 1023) / 1024;
  int base = t * per;
  int s = 0;
  for (int i = 0; i < per; ++i) {
    int idx = base + i;
    if (idx < NNODE) s += deg[idx];
  }
  sums[t] = s;
  __syncthreads();
  for (int off = 1; off < 1024; off <<= 1) {
    int v = (t >= off) ? sums[t - off] : 0;
    __syncthreads();
    if (t >= off) sums[t] += v;
    __syncthreads();
  }
  int run = (t == 0) ? 0 : sums[t - 1];
  for (int i = 0; i < per; ++i) {
    int idx = base + i;
    if (idx < NNODE) {
      row_ptr[idx] = run;
      cursor[idx] = run;
      run += deg[idx];
    }
  }
  if (t == 1023) row_ptr[NNODE] = run;
}

static __global__ void fill_kernel(const int* __restrict__ src, const int* __restrict__ dst,
                                   int* __restrict__ cursor, int2* __restrict__ elist) {
  int i = blockIdx.x * 256 + threadIdx.x;
  if (i < NEDGE) {
    int d = dst[i];
    int p = atomicAdd(&cursor[d], 1);
    elist[p] = make_int2(i, src[i]);
  }
}

// ---------------------------------------------------------------- W split (once/call):
// Wt[hi|lo][c*2+g][n][136 k] bf16 (transposed so B-frag reads 8 consecutive k)
static __global__ void wsplit_kernel(const float* __restrict__ W1, const float* __restrict__ W2,
                                     unsigned short* __restrict__ whi,
                                     unsigned short* __restrict__ wlo) {
  int idx = blockIdx.x * 256 + threadIdx.x;
  if (idx >= 6 * 16384) return;
  int cg = idx >> 14;            // c*2+g
  int rem = idx & 16383;
  int k = rem >> 7, n = rem & 127;
  int c = cg >> 1, g = cg & 1;
  float v = (g ? W2 : W1)[c * 16384 + k * 128 + n];
  unsigned u = __float_as_uint(v);
  unsigned hb = u >> 16;                             // truncate -> lo captures residue
  float hf = __uint_as_float(hb << 16);
  unsigned lb = __float_as_uint(v - hf) >> 16;
  int o = cg * 17408 + n * 136 + k;                  // 17408 = 128*136
  whi[o] = (unsigned short)hb;
  wlo[o] = (unsigned short)lb;
}

// ---------------------------------------------------------------- gather:
// out[n] = x[n] + sum_{e->n} relu(x[src]+ea[e]); 1 node/wave, unroll x4; ea via NT loads
static __global__ __launch_bounds__(256) void gather_kernel(
    const float* __restrict__ x, const float* __restrict__ ea,
    const int* __restrict__ row_ptr, const int2* __restrict__ elist,
    float* __restrict__ out) {
  int wave = threadIdx.x >> 6;
  int lane = threadIdx.x & 63;
  int node = blockIdx.x * 4 + wave;
  if (node >= NNODE) return;
  const float2* x2 = (const float2*)x;
  const double* ed = (const double*)ea;              // 8B NT loads
  float2 a0 = x2[(size_t)node * 64 + lane];
  float2 a1 = make_float2(0.f, 0.f);
  float2 a2 = make_float2(0.f, 0.f);
  float2 a3 = make_float2(0.f, 0.f);
  int j  = row_ptr[node];
  int je = row_ptr[node + 1];
  for (; j + 4 <= je; j += 4) {
    int2 e0 = elist[j], e1 = elist[j + 1], e2i = elist[j + 2], e3 = elist[j + 3];
    float2 xv0 = x2[(size_t)e0.y * 64 + lane];
    double d0 = __builtin_nontemporal_load(&ed[(size_t)e0.x * 64 + lane]);
    float2 xv1 = x2[(size_t)e1.y * 64 + lane];
    double d1 = __builtin_nontemporal_load(&ed[(size_t)e1.x * 64 + lane]);
    float2 xv2 = x2[(size_t)e2i.y * 64 + lane];
    double d2 = __builtin_nontemporal_load(&ed[(size_t)e2i.x * 64 + lane]);
    float2 xv3 = x2[(size_t)e3.y * 64 + lane];
    double d3 = __builtin_nontemporal_load(&ed[(size_t)e3.x * 64 + lane]);
    float2 ev0 = *(float2*)&d0, ev1 = *(float2*)&d1;
    float2 ev2 = *(float2*)&d2, ev3 = *(float2*)&d3;
    a0.x += fmaxf(xv0.x + ev0.x, 0.f); a0.y += fmaxf(xv0.y + ev0.y, 0.f);
    a1.x += fmaxf(xv1.x + ev1.x, 0.f); a1.y += fmaxf(xv1.y + ev1.y, 0.f);
    a2.x += fmaxf(xv2.x + ev2.x, 0.f); a2.y += fmaxf(xv2.y + ev2.y, 0.f);
    a3.x += fmaxf(xv3.x + ev3.x, 0.f); a3.y += fmaxf(xv3.y + ev3.y, 0.f);
  }
  for (; j < je; ++j) {
    int2 es = elist[j];
    float2 xv = x2[(size_t)es.y * 64 + lane];
    double d0 = __builtin_nontemporal_load(&ed[(size_t)es.x * 64 + lane]);
    float2 ev = *(float2*)&d0;
    a0.x += fmaxf(xv.x + ev.x, 0.f);
    a0.y += fmaxf(xv.y + ev.y, 0.f);
  }
  a0.x += a1.x + a2.x + a3.x;
  a0.y += a1.y + a2.y + a3.y;
  ((float2*)out)[(size_t)node * 64 + lane] = a0;
}

// ---------------------------------------------------------------- MFMA MLP:
// xout = x + [relu?](relu(in@W1+b1)@W2+b2), bf16 hi/lo split (3 mfma/product).
// 64 rows/block, wave w owns rows w*16..+15 x all 128 cols (8 16x16 tiles).
// LDS: W chunk hi/lo 36.9K + t fp32 33.8K = 70.7K -> 2 blocks/CU.
static __global__ __launch_bounds__(256) void mlp_mfma(
    const float* __restrict__ in, const float* __restrict__ xres,
    const unsigned short* __restrict__ wt1hi, const unsigned short* __restrict__ wt1lo,
    const unsigned short* __restrict__ wt2hi, const unsigned short* __restrict__ wt2lo,
    const float* __restrict__ b1, const float* __restrict__ b2,
    float* __restrict__ xout, int relu_out) {
  __shared__ unsigned short WbHi[128 * 72];          // [n][72] k-chunk of 64
  __shared__ unsigned short WbLo[128 * 72];
  __shared__ float Ts[64 * 132];                     // t, fp32, ld=132
  const int tid = threadIdx.x;
  const int w = tid >> 6, l = tid & 63;
  const int lm = l & 15, quad = l >> 4;
  const int row0 = blockIdx.x * 64;

  float b1v[8], b2v[8];
#pragma unroll
  for (int t = 0; t < 8; ++t) { b1v[t] = b1[t * 16 + lm]; b2v[t] = b2[t * 16 + lm]; }

  f32x4 acc[8];
#pragma unroll
  for (int t = 0; t < 8; ++t) acc[t] = (f32x4){0.f, 0.f, 0.f, 0.f};

  // A row for frag loads (clamped; tail stores are guarded)
  int arow = row0 + w * 16 + lm;
  if (arow >= NNODE) arow = NNODE - 1;

  // ---- GEMM 1: acc = in @ W1  (A from global, split on the fly)
  for (int kc = 0; kc < 128; kc += 64) {
    __syncthreads();
    for (int idx = tid; idx < 128 * 8; idx += 256) {
      int n = idx >> 3, seg = idx & 7;
      *(uint4*)&WbHi[n * 72 + seg * 8] = *(const uint4*)&wt1hi[n * 136 + kc + seg * 8];
      *(uint4*)&WbLo[n * 72 + seg * 8] = *(const uint4*)&wt1lo[n * 136 + kc + seg * 8];
    }
    __syncthreads();
#pragma unroll
    for (int ks = 0; ks < 64; ks += 32) {
      const float* ap = in + (size_t)arow * 128 + kc + ks + quad * 8;
      float4 av0 = *(const float4*)ap;
      float4 av1 = *(const float4*)(ap + 4);
      float av[8] = {av0.x, av0.y, av0.z, av0.w, av1.x, av1.y, av1.z, av1.w};
      bf16x8 ah, al;
#pragma unroll
      for (int jj = 0; jj < 8; ++jj) {
        unsigned u = __float_as_uint(av[jj]);
        unsigned hb = u >> 16;
        float hf = __uint_as_float(hb << 16);
        unsigned lb = __float_as_uint(av[jj] - hf) >> 16;
        ah[jj] = (short)hb; al[jj] = (short)lb;
      }
#pragma unroll
      for (int t = 0; t < 8; ++t) {
        int off = (t * 16 + lm) * 72 + ks + quad * 8;
        bf16x8 bh = *(const bf16x8*)&WbHi[off];
        bf16x8 bl = *(const bf16x8*)&WbLo[off];
        acc[t] = __builtin_amdgcn_mfma_f32_16x16x32_bf16(ah, bh, acc[t], 0, 0, 0);
        acc[t] = __builtin_amdgcn_mfma_f32_16x16x32_bf16(ah, bl, acc[t], 0, 0, 0);
        acc[t] = __builtin_amdgcn_mfma_f32_16x16x32_bf16(al, bh, acc[t], 0, 0, 0);
      }
    }
  }
  __syncthreads();

  // t = relu(acc + b1) -> Ts ; C layout: row = w*16 + quad*4 + r, col = t*16+lm
#pragma unroll
  for (int t = 0; t < 8; ++t)
#pragma unroll
    for (int r = 0; r < 4; ++r)
      Ts[(w * 16 + quad * 4 + r) * 132 + t * 16 + lm] = fmaxf(acc[t][r] + b1v[t], 0.f);

#pragma unroll
  for (int t = 0; t < 8; ++t) acc[t] = (f32x4){0.f, 0.f, 0.f, 0.f};
  __syncthreads();

  // ---- GEMM 2: acc = t @ W2  (A from Ts fp32, split on the fly)
  for (int kc = 0; kc < 128; kc += 64) {
    __syncthreads();
    for (int idx = tid; idx < 128 * 8; idx += 256) {
      int n = idx >> 3, seg = idx & 7;
      *(uint4*)&WbHi[n * 72 + seg * 8] = *(const uint4*)&wt2hi[n * 136 + kc + seg * 8];
      *(uint4*)&WbLo[n * 72 + seg * 8] = *(const uint4*)&wt2lo[n * 136 + kc + seg * 8];
    }
    __syncthreads();
#pragma unroll
    for (int ks = 0; ks < 64; ks += 32) {
      const float* tp = &Ts[(w * 16 + lm) * 132 + kc + ks + quad * 8];
      float4 av0 = *(const float4*)tp;
      float4 av1 = *(const float4*)(tp + 4);
      float av[8] = {av0.x, av0.y, av0.z, av0.w, av1.x, av1.y, av1.z, av1.w};
      bf16x8 ah, al;
#pragma unroll
      for (int jj = 0; jj < 8; ++jj) {
        unsigned u = __float_as_uint(av[jj]);
        unsigned hb = u >> 16;
        float hf = __uint_as_float(hb << 16);
        unsigned lb = __float_as_uint(av[jj] - hf) >> 16;
        ah[jj] = (short)hb; al[jj] = (short)lb;
      }
#pragma unroll
      for (int t = 0; t < 8; ++t) {
        int off = (t * 16 + lm) * 72 + ks + quad * 8;
        bf16x8 bh = *(const bf16x8*)&WbHi[off];
        bf16x8 bl = *(const bf16x8*)&WbLo[off];
        acc[t] = __builtin_amdgcn_mfma_f32_16x16x32_bf16(ah, bh, acc[t], 0, 0, 0);
        acc[t] = __builtin_amdgcn_mfma_f32_16x16x32_bf16(ah, bl, acc[t], 0, 0, 0);
        acc[t] = __builtin_amdgcn_mfma_f32_16x16x32_bf16(al, bh, acc[t], 0, 0, 0);
      }
    }
  }

  // epilogue: bias, optional relu, residual, store (scalar but coalesced 4-row x 16-col)
#pragma unroll
  for (int t = 0; t < 8; ++t) {
#pragma unroll
    for (int r = 0; r < 4; ++r) {
      int row = row0 + w * 16 + quad * 4 + r;
      if (row < NNODE) {
        int col = t * 16 + lm;
        float v = acc[t][r] + b2v[t];
        if (relu_out) v = fmaxf(v, 0.f);
        v += xres[(size_t)row * 128 + col];
        xout[(size_t)row * 128 + col] = v;
      }
    }
  }
}

extern "C" void kernel_launch(void* const* d_in, const int* in_sizes, int n_in,
                              void* d_out, int out_size, void* d_ws, size_t ws_size,
                              hipStream_t stream) {
  const int*   z   = (const int*)d_in[0];
  const int*   ei  = (const int*)d_in[1];
  const float* ea  = (const float*)d_in[2];
  const float* emb = (const float*)d_in[3];
  const float* W1  = (const float*)d_in[4];
  const float* b1  = (const float*)d_in[5];
  const float* W2  = (const float*)d_in[6];
  const float* b2  = (const float*)d_in[7];
  float* outp = (float*)d_out;

  char* ws = (char*)d_ws;
  float* xbuf   = (float*)(ws + 0);
  float* obuf   = (float*)(ws + 25600000);
  int*   deg    = (int*)  (ws + 51200000);
  int*   cursor = (int*)  (ws + 51400000);
  int*   rowptr = (int*)  (ws + 51600000);
  int2*  elist  = (int2*) (ws + 51800016);
  unsigned short* whi = (unsigned short*)(ws + 57000000);  // 6*17408*2 B = 208,896
  unsigned short* wlo = (unsigned short*)(ws + 57250000);

  const int* srcv = ei;
  const int* dstv = ei + NEDGE;

  hipMemsetAsync(deg, 0, NNODE * sizeof(int), stream);
  embed_kernel<<<(NNODE * 32 + 255) / 256, 256, 0, stream>>>(z, emb, xbuf);
  hist_kernel<<<(NEDGE + 255) / 256, 256, 0, stream>>>(dstv, deg);
  scan_kernel<<<1, 1024, 0, stream>>>(deg, rowptr, cursor);
  fill_kernel<<<(NEDGE + 255) / 256, 256, 0, stream>>>(srcv, dstv, cursor, elist);
  wsplit_kernel<<<(6 * 16384 + 255) / 256, 256, 0, stream>>>(W1, W2, whi, wlo);

  for (int i = 0; i < 3; ++i) {
    gather_kernel<<<(NNODE + 3) / 4, 256, 0, stream>>>(xbuf, ea, rowptr, elist, obuf);
    float* xo = (i == 2) ? outp : xbuf;
    mlp_mfma<<<(NNODE + 63) / 64, 256, 0, stream>>>(
        obuf, xbuf,
        whi + (size_t)(i * 2 + 0) * 17408, wlo + (size_t)(i * 2 + 0) * 17408,
        whi + (size_t)(i * 2 + 1) * 17408, wlo + (size_t)(i * 2 + 1) * 17408,
        b1 + (size_t)i * HID, b2 + (size_t)i * HID,
        xo, (i < 2) ? 1 : 0);
  }
}